// Round 14
// baseline (205.014 us; speedup 1.0000x reference)
//
#include <hip/hip_runtime.h>

#define N 8192
#define C 64
#define S 16

static constexpr float BN_INV = 0.9999950000374997f; // 1/sqrt(1+1e-5)
static constexpr float LN_EPS = 1e-5f;

typedef _Float16 f16x8 __attribute__((ext_vector_type(8)));
typedef _Float16 f16x4 __attribute__((ext_vector_type(4)));
typedef float f32x4 __attribute__((ext_vector_type(4)));

__device__ __forceinline__ void sort2(unsigned& x, unsigned& y)
{
    unsigned lo = min(x, y);
    unsigned hi = max(x, y);
    x = lo;
    y = hi;
}

__device__ __forceinline__ unsigned med3u(unsigned a, unsigned b, unsigned c)
{
    unsigned r;
    asm("v_med3_u32 %0, %1, %2, %3" : "=v"(r) : "v"(a), "v"(b), "v"(c));
    return r;
}

__device__ __forceinline__ void insert4(unsigned& a0, unsigned& a1,
                                        unsigned& a2, unsigned& a3,
                                        unsigned k)
{
    unsigned m = min(a3, k);
    unsigned n1 = med3u(a0, a1, m);
    unsigned n2 = med3u(a1, a2, m);
    a3 = max(a2, m);
    a0 = min(a0, m);
    a1 = n1;
    a2 = n2;
}

__device__ __forceinline__ int mbcnt64(unsigned long long m)
{
    int lo = __builtin_amdgcn_mbcnt_lo((unsigned)m, 0);
    return __builtin_amdgcn_mbcnt_hi((unsigned)(m >> 32), lo);
}

// ---------------------------------------------------------------------------
// K1: FUSED knn + qkv + weight-prep (R12 structure). qkv branch additionally
// writes its feats A-frags as f16 into hcat[row][0..63] — free (au regs are
// already exactly the hcat A-layout).
// ---------------------------------------------------------------------------
__global__ __launch_bounds__(512) void qkv_knn_kernel(
    const int4* __restrict__ idx4, int* __restrict__ knn_out,
    const float* __restrict__ feats,
    const float* __restrict__ Wq, const float* __restrict__ bq,
    const float* __restrict__ Wk, const float* __restrict__ bk,
    const float* __restrict__ Wv, const float* __restrict__ bv,
    float* __restrict__ xq, float* __restrict__ xk, float* __restrict__ xv,
    const float* __restrict__ Ww1, const float* __restrict__ Ww2,
    const float* __restrict__ Wc1, const float* __restrict__ Wc2,
    const float* __restrict__ Wc3,
    _Float16* __restrict__ W1tG, _Float16* __restrict__ W2tG,
    _Float16* __restrict__ Wc1tG, _Float16* __restrict__ Wc2tG,
    _Float16* __restrict__ Wc3tG, _Float16* __restrict__ hcat)
{
    extern __shared__ char smem[];
    const int t = threadIdx.x;
    const int lane = t & 63;
    const int wv = t >> 6;
    if (blockIdx.x < 1024) {
        unsigned* pk = (unsigned*)smem;
        const int q = blockIdx.x * 8 + wv;
#pragma unroll
        for (int i = 0; i < 16; i++) {
            int j = i * 512 + t;
            int4 c = idx4[j];
            pk[j] = (unsigned)c.y | ((unsigned)c.z << 8) |
                    ((unsigned)c.w << 16);
        }
        const int4 qc = idx4[q];
        const int qx = qc.y, qy = qc.z, qz = qc.w;
        const unsigned qq = (unsigned)(qx * qx + qy * qy + qz * qz);
#if __has_builtin(__builtin_amdgcn_udot4)
        const unsigned qpk2 = (unsigned)(2 * qx) | ((unsigned)(2 * qy) << 8) |
                              ((unsigned)(2 * qz) << 16);
#endif
        unsigned a0 = 0xFFFFFFFFu, a1 = 0xFFFFFFFFu, a2 = 0xFFFFFFFFu,
                 a3 = 0xFFFFFFFFu;
        unsigned b0 = 0xFFFFFFFFu, b1 = 0xFFFFFFFFu, b2 = 0xFFFFFFFFu,
                 b3 = 0xFFFFFFFFu;
        __syncthreads();
        const uint4* pk4 = (const uint4*)pk;
#pragma unroll 4
        for (int i = 0; i < 32; ++i) {
            uint4 cd = pk4[i * 64 + lane];
            const unsigned j0 = (unsigned)((i * 64 + lane) * 4);
#if __has_builtin(__builtin_amdgcn_udot4)
            unsigned d20 = __builtin_amdgcn_udot4(cd.x, cd.x, qq, false) -
                           __builtin_amdgcn_udot4(cd.x, qpk2, 0u, false);
            unsigned d21 = __builtin_amdgcn_udot4(cd.y, cd.y, qq, false) -
                           __builtin_amdgcn_udot4(cd.y, qpk2, 0u, false);
            unsigned d22 = __builtin_amdgcn_udot4(cd.z, cd.z, qq, false) -
                           __builtin_amdgcn_udot4(cd.z, qpk2, 0u, false);
            unsigned d23 = __builtin_amdgcn_udot4(cd.w, cd.w, qq, false) -
                           __builtin_amdgcn_udot4(cd.w, qpk2, 0u, false);
#else
            unsigned d20, d21, d22, d23;
            {
                unsigned ps[4] = {cd.x, cd.y, cd.z, cd.w};
                unsigned ds[4];
#pragma unroll
                for (int c = 0; c < 4; c++) {
                    int x = (int)(ps[c] & 255u), y = (int)((ps[c] >> 8) & 255u),
                        z = (int)(ps[c] >> 16);
                    int dx = x - qx, dy = y - qy, dz = z - qz;
                    ds[c] = (unsigned)(dx * dx + dy * dy + dz * dz);
                }
                d20 = ds[0]; d21 = ds[1]; d22 = ds[2]; d23 = ds[3];
            }
#endif
            insert4(a0, a1, a2, a3, (d20 << 13) + j0);
            insert4(a0, a1, a2, a3, (d21 << 13) + j0 + 1);
            insert4(b0, b1, b2, b3, (d22 << 13) + j0 + 2);
            insert4(b0, b1, b2, b3, (d23 << 13) + j0 + 3);
        }
        unsigned t0 = min(a0, b3), t1 = min(a1, b2), t2 = min(a2, b1),
                 t3 = min(a3, b0);
        sort2(t0, t2); sort2(t1, t3); sort2(t0, t1); sort2(t2, t3);
        sort2(t1, t2);
        unsigned prefix = 0u;
#pragma unroll
        for (int bit = 28; bit >= 0; --bit) {
            unsigned cand = prefix | (1u << bit);
            int c = __popcll(__ballot(t0 < cand)) +
                    __popcll(__ballot(t1 < cand)) +
                    __popcll(__ballot(t2 < cand)) +
                    __popcll(__ballot(t3 < cand));
            if (c < 16) prefix = cand;
        }
        const unsigned T = prefix;
        {
            unsigned long long m0 = __ballot(t0 <= T);
            unsigned long long m1 = __ballot(t1 <= T);
            unsigned long long m2 = __ballot(t2 <= T);
            unsigned long long m3 = __ballot(t3 <= T);
            int base1 = __popcll(m0);
            int base2 = base1 + __popcll(m1);
            int base3 = base2 + __popcll(m2);
            int* dst = knn_out + q * 16;
            if (t0 <= T) dst[mbcnt64(m0)] = (int)(t0 & 8191u);
            if (t1 <= T) dst[base1 + mbcnt64(m1)] = (int)(t1 & 8191u);
            if (t2 <= T) dst[base2 + mbcnt64(m2)] = (int)(t2 & 8191u);
            if (t3 <= T) dst[base3 + mbcnt64(m3)] = (int)(t3 & 8191u);
        }
        unsigned long long bad = __ballot(t3 < T);
        if (bad) {
            unsigned c0 = 0xFFFFFFFFu, c1 = 0xFFFFFFFFu, c2 = 0xFFFFFFFFu,
                     c3 = 0xFFFFFFFFu, c4 = 0xFFFFFFFFu, c5 = 0xFFFFFFFFu,
                     c6 = 0xFFFFFFFFu, c7 = 0xFFFFFFFFu, c8 = 0xFFFFFFFFu,
                     c9 = 0xFFFFFFFFu, c10 = 0xFFFFFFFFu, c11 = 0xFFFFFFFFu,
                     c12 = 0xFFFFFFFFu, c13 = 0xFFFFFFFFu, c14 = 0xFFFFFFFFu,
                     c15 = 0xFFFFFFFFu;
            for (int i = 0; i < 128; ++i) {
                int j = i * 64 + lane;
                int4 cd = idx4[j];
                int dx = cd.y - qx, dy = cd.z - qy, dz = cd.w - qz;
                unsigned d2 = (unsigned)(dx * dx + dy * dy + dz * dz);
                unsigned key = (d2 << 13) + (unsigned)j;
                c15 = min(c15, key);
                sort2(c14, c15); sort2(c13, c14); sort2(c12, c13);
                sort2(c11, c12); sort2(c10, c11); sort2(c9, c10);
                sort2(c8, c9);   sort2(c7, c8);   sort2(c6, c7);
                sort2(c5, c6);   sort2(c4, c5);   sort2(c3, c4);
                sort2(c2, c3);   sort2(c1, c2);   sort2(c0, c1);
            }
            for (int r = 0; r < 16; ++r) {
                unsigned m = c0;
                m = min(m, (unsigned)__shfl_xor((int)m, 1, 64));
                m = min(m, (unsigned)__shfl_xor((int)m, 2, 64));
                m = min(m, (unsigned)__shfl_xor((int)m, 4, 64));
                m = min(m, (unsigned)__shfl_xor((int)m, 8, 64));
                m = min(m, (unsigned)__shfl_xor((int)m, 16, 64));
                m = min(m, (unsigned)__shfl_xor((int)m, 32, 64));
                if (lane == r) knn_out[q * 16 + r] = (int)(m & 8191u);
                bool win = (c0 == m);
                c0 = win ? c1 : c0;    c1 = win ? c2 : c1;
                c2 = win ? c3 : c2;    c3 = win ? c4 : c3;
                c4 = win ? c5 : c4;    c5 = win ? c6 : c5;
                c6 = win ? c7 : c6;    c7 = win ? c8 : c7;
                c8 = win ? c9 : c8;    c9 = win ? c10 : c9;
                c10 = win ? c11 : c10; c11 = win ? c12 : c11;
                c12 = win ? c13 : c12; c13 = win ? c14 : c13;
                c14 = win ? c15 : c14; c15 = win ? 0xFFFFFFFFu : c15;
            }
        }
    } else if (blockIdx.x < 1088) {
        _Float16* sBt = (_Float16*)smem;
        float* sbias = (float*)(smem + 192 * 72 * 2);
        const int col = lane & 15, g = lane >> 4;
        const int bid2 = blockIdx.x - 1024;
        const int row0w = bid2 * 128 + wv * 16;
        {
            const float* Ws[3] = {Wq, Wk, Wv};
#pragma unroll
            for (int m = 0; m < 3; m++) {
                int k = t >> 3, nb = (t & 7) * 8;
                const float4* src = (const float4*)(Ws[m] + k * 64 + nb);
                float4 w0 = src[0], w1 = src[1];
                _Float16* dst = &sBt[(m * 64 + nb) * 72 + k];
                dst[0 * 72] = (_Float16)w0.x; dst[1 * 72] = (_Float16)w0.y;
                dst[2 * 72] = (_Float16)w0.z; dst[3 * 72] = (_Float16)w0.w;
                dst[4 * 72] = (_Float16)w1.x; dst[5 * 72] = (_Float16)w1.y;
                dst[6 * 72] = (_Float16)w1.z; dst[7 * 72] = (_Float16)w1.w;
            }
            if (t < 64) sbias[t] = bq[t];
            else if (t < 128) sbias[t] = bk[t - 64];
            else if (t < 192) sbias[t] = bv[t - 128];
        }
        __syncthreads();
        f16x8 au[2];
#pragma unroll
        for (int kc = 0; kc < 2; kc++) {
            const float4* src = (const float4*)
                (feats + (row0w + col) * 64 + kc * 32 + g * 8);
            float4 v0 = src[0], v1 = src[1];
            au[kc][0] = (_Float16)v0.x; au[kc][1] = (_Float16)v0.y;
            au[kc][2] = (_Float16)v0.z; au[kc][3] = (_Float16)v0.w;
            au[kc][4] = (_Float16)v1.x; au[kc][5] = (_Float16)v1.y;
            au[kc][6] = (_Float16)v1.z; au[kc][7] = (_Float16)v1.w;
            // free hcat feats-half write (au is exactly the hcat A-layout)
            *(f16x8*)&hcat[(row0w + col) * 128 + kc * 32 + g * 8] = au[kc];
        }
        float* outs[3] = {xq, xk, xv};
#pragma unroll
        for (int f = 0; f < 12; f++) {
            f32x4 acc;
            float bias = sbias[f * 16 + col];
#pragma unroll
            for (int r = 0; r < 4; r++) acc[r] = bias;
#pragma unroll
            for (int kc = 0; kc < 2; kc++) {
                f16x8 bw = *(const f16x8*)
                    &sBt[(f * 16 + col) * 72 + kc * 32 + g * 8];
                acc = __builtin_amdgcn_mfma_f32_16x16x32_f16(au[kc], bw, acc,
                                                             0, 0, 0);
            }
            float* o = outs[f >> 2];
            int cg = (f & 3) * 16 + col;
#pragma unroll
            for (int r = 0; r < 4; r++)
                o[(row0w + g * 4 + r) * 64 + cg] = acc[r];
        }
    } else {
        for (int o = t; o < 8192; o += 512) {
            int n = o >> 6, k = o & 63;
            W1tG[o] = (_Float16)Ww1[k * 128 + n];
        }
        for (int o = t; o < 8192; o += 512) {
            int n = o >> 7, k = o & 127;
            W2tG[o] = (_Float16)Ww2[k * 64 + n];
        }
        for (int o = t; o < 16384; o += 512) {
            int n = o >> 7, k = o & 127;
            Wc1tG[o] = (_Float16)Wc1[k * 128 + n];
        }
        for (int o = t; o < 16384; o += 512) {
            int n = o >> 7, k = o & 127;
            Wc2tG[o] = (_Float16)Wc2[k * 128 + n];
        }
        for (int o = t; o < 8192; o += 512) {
            int n = o >> 7, k = o & 127;
            Wc3tG[o] = (_Float16)Wc3[k * 64 + n];
        }
    }
}

// ---------------------------------------------------------------------------
// K2: MFMA vector-attention, LOW-LDS (R13 structure; best known). Output now
// written f16 into hcat[q][64..127] (head is the sole consumer).
// ---------------------------------------------------------------------------
__global__ __launch_bounds__(512, 6) void attn_kernel(
    const int4* __restrict__ idx4, const int* __restrict__ knn,
    const float* __restrict__ xq, const float* __restrict__ xk,
    const float* __restrict__ xv,
    const float* __restrict__ Wp1, const float* __restrict__ pg,
    const float* __restrict__ pb, const float* __restrict__ Wp2,
    const float* __restrict__ bp2,
    const float* __restrict__ wg1, const float* __restrict__ wb1,
    const _Float16* __restrict__ W1tG,
    const float* __restrict__ wg2, const float* __restrict__ wb2,
    const _Float16* __restrict__ W2tG,
    _Float16* __restrict__ hcat)
{
    __shared__ _Float16 sW1t[128 * 72];
    __shared__ _Float16 sW2t[64 * 136];
    __shared__ _Float16 sscr[8][16 * 40];
    __shared__ float sWp1[48], sPg[16], sPb[16];
    __shared__ float sg2[128], sb2[128];

    const int t = threadIdx.x;
    const int lane = t & 63;
    const int wv = t >> 6;
    const int col = lane & 15, g = lane >> 4;
    const int q = blockIdx.x * 8 + wv;

    const int jA = knn[q * 16 + col];
    const int4 jC = *(const int4*)(knn + q * 16 + g * 4);
    const int jr[4] = {jC.x, jC.y, jC.z, jC.w};
    const int4 pc = idx4[jA];
    const int4 qc = idx4[q];
    float xqv[4], xkv[4][4], xvv[4][4];
#pragma unroll
    for (int f = 0; f < 4; f++) xqv[f] = xq[q * 64 + f * 16 + col];
#pragma unroll
    for (int r = 0; r < 4; r++)
#pragma unroll
        for (int f = 0; f < 4; f++) {
            xkv[r][f] = xk[jr[r] * 64 + f * 16 + col];
            xvv[r][f] = xv[jr[r] * 64 + f * 16 + col];
        }

    for (int i = t; i < 1024; i += 512) {
        int n = i >> 3, ko = i & 7;
        *(f16x8*)&sW1t[n * 72 + ko * 8] =
            *(const f16x8*)&W1tG[n * 64 + ko * 8];
    }
    for (int i = t; i < 1024; i += 512) {
        int m = i >> 4, ko = i & 15;
        *(f16x8*)&sW2t[m * 136 + ko * 8] =
            *(const f16x8*)&W2tG[m * 128 + ko * 8];
    }
    if (t < 48) sWp1[t] = Wp1[t];
    if (t < 16) { sPg[t] = pg[t] * BN_INV; sPb[t] = pb[t]; }
    if (t >= 64 && t < 192) {
        int o = t - 64;
        sg2[o] = wg2[o] * BN_INV;
        sb2[o] = wb2[o];
    }

    float g1c[4], b1c[4], bp2c[4];
#pragma unroll
    for (int f = 0; f < 4; f++) {
        int c = f * 16 + col;
        g1c[f] = wg1[c] * BN_INV; b1c[f] = wb1[c];
        bp2c[f] = bp2[c];
    }
    __syncthreads();

    _Float16* scr = sscr[wv];

    const float px = (float)(pc.y - qc.y);
    const float py = (float)(pc.z - qc.z);
    const float pz = (float)(pc.w - qc.w);
    f32x4 pr[4];
#if __has_builtin(__builtin_amdgcn_mfma_f32_16x16x16f16)
    {
        f16x4 aph;
#pragma unroll
        for (int j = 0; j < 4; j++) {
            int h = g * 4 + j;
            float v = px * sWp1[h] + py * sWp1[16 + h] + pz * sWp1[32 + h];
            v = fmaxf(v * sPg[h] + sPb[h], 0.f);
            aph[j] = (_Float16)v;
        }
#pragma unroll
        for (int f = 0; f < 4; f++) {
            f16x4 bP;
#pragma unroll
            for (int j = 0; j < 4; j++)
                bP[j] = (_Float16)Wp2[(g * 4 + j) * 64 + f * 16 + col];
            f32x4 cini;
#pragma unroll
            for (int r = 0; r < 4; r++) cini[r] = bp2c[f];
            pr[f] = __builtin_amdgcn_mfma_f32_16x16x16f16(aph, bP, cini,
                                                          0, 0, 0);
        }
    }
#else
    {
        f16x8 aph;
#pragma unroll
        for (int j = 0; j < 8; j++) {
            int h = g * 8 + j;
            float v = 0.f;
            if (g < 2) {
                v = px * sWp1[h] + py * sWp1[16 + h] + pz * sWp1[32 + h];
                v = fmaxf(v * sPg[h] + sPb[h], 0.f);
            }
            aph[j] = (_Float16)v;
        }
#pragma unroll
        for (int f = 0; f < 4; f++) {
            f16x8 bP;
#pragma unroll
            for (int j = 0; j < 8; j++) {
                int h = g * 8 + j;
                bP[j] = (g < 2) ? (_Float16)Wp2[h * 64 + f * 16 + col]
                                : (_Float16)0.f;
            }
            f32x4 cini;
#pragma unroll
            for (int r = 0; r < 4; r++) cini[r] = bp2c[f];
            pr[f] = __builtin_amdgcn_mfma_f32_16x16x32_f16(aph, bP, cini,
                                                           0, 0, 0);
        }
    }
#endif
    f32x4 vvr[4];
    f32x4 acc1[8];
#pragma unroll
    for (int f = 0; f < 8; f++)
#pragma unroll
        for (int r = 0; r < 4; r++) acc1[f][r] = 0.f;
#pragma unroll
    for (int kc = 0; kc < 2; kc++) {
#pragma unroll
        for (int fp = 0; fp < 2; fp++) {
            int f = kc * 2 + fp;
#pragma unroll
            for (int r = 0; r < 4; r++) {
                float w0 = xkv[r][f] - xqv[f] + pr[f][r];
                float uu = fmaxf(w0 * g1c[f] + b1c[f], 0.f);
                scr[(g * 4 + r) * 40 + fp * 16 + col] = (_Float16)uu;
                vvr[f][r] = xvv[r][f] + pr[f][r];
            }
        }
        f16x8 au = *(const f16x8*)&scr[col * 40 + g * 8];
#pragma unroll
        for (int f = 0; f < 8; f++) {
            f16x8 bw = *(const f16x8*)
                &sW1t[(f * 16 + col) * 72 + kc * 32 + g * 8];
            acc1[f] = __builtin_amdgcn_mfma_f32_16x16x32_f16(au, bw, acc1[f],
                                                             0, 0, 0);
        }
    }
    _Float16 o1v[8][4];
#pragma unroll
    for (int f = 0; f < 8; f++) {
        float gn = sg2[f * 16 + col], bs = sb2[f * 16 + col];
#pragma unroll
        for (int r = 0; r < 4; r++)
            o1v[f][r] = (_Float16)fmaxf(acc1[f][r] * gn + bs, 0.f);
    }
    f32x4 accL[4];
#pragma unroll
    for (int f = 0; f < 4; f++)
#pragma unroll
        for (int r = 0; r < 4; r++) accL[f][r] = 0.f;
#pragma unroll
    for (int c = 0; c < 4; c++) {
#pragma unroll
        for (int fp = 0; fp < 2; fp++)
#pragma unroll
            for (int r = 0; r < 4; r++)
                scr[(g * 4 + r) * 40 + fp * 16 + col] = o1v[c * 2 + fp][r];
        f16x8 ao = *(const f16x8*)&scr[col * 40 + g * 8];
#pragma unroll
        for (int f = 0; f < 4; f++) {
            f16x8 bw = *(const f16x8*)
                &sW2t[(f * 16 + col) * 136 + c * 32 + g * 8];
            accL[f] = __builtin_amdgcn_mfma_f32_16x16x32_f16(ao, bw, accL[f],
                                                             0, 0, 0);
        }
    }
    float outv[4];
#pragma unroll
    for (int f = 0; f < 4; f++) {
        float mx = fmaxf(fmaxf(accL[f][0], accL[f][1]),
                         fmaxf(accL[f][2], accL[f][3]));
        mx = fmaxf(mx, __shfl_xor(mx, 16, 64));
        mx = fmaxf(mx, __shfl_xor(mx, 32, 64));
        float sum = 0.f, part = 0.f;
#pragma unroll
        for (int r = 0; r < 4; r++) {
            float e = __expf(accL[f][r] - mx);
            sum += e;
            part = fmaf(e, vvr[f][r], part);
        }
        sum += __shfl_xor(sum, 16, 64);
        sum += __shfl_xor(sum, 32, 64);
        part += __shfl_xor(part, 16, 64);
        part += __shfl_xor(part, 32, 64);
        outv[f] = part / sum;
    }
    float val = (g == 0) ? outv[0]
              : (g == 1) ? outv[1]
              : (g == 2) ? outv[2] : outv[3];
    hcat[q * 128 + 64 + lane] = (_Float16)val;
}

// ---------------------------------------------------------------------------
// K3: BARRIER-FREE wave-autonomous head. 256 blocks x 128 thr; each wave
// owns 16 rows end-to-end: A-frags streamed from f16 hcat, B-frags streamed
// from pre-transposed f16 weights (L2-hot), h1/h2 transposed through a
// wave-private 16x136 LDS chunk (in-order within the wave -> zero
// __syncthreads), LN in registers via width-16 shuffles.
// ---------------------------------------------------------------------------
__global__ __launch_bounds__(128) void head_kernel(
    const _Float16* __restrict__ hcat,
    const _Float16* __restrict__ Wc1tG, const float* __restrict__ cg1,
    const float* __restrict__ cb1, const _Float16* __restrict__ Wc2tG,
    const float* __restrict__ cg2, const float* __restrict__ cb2,
    const _Float16* __restrict__ Wc3tG, const float* __restrict__ bc3,
    const float* __restrict__ lng, const float* __restrict__ lnb,
    float* __restrict__ out)
{
    __shared__ _Float16 sh[2][16 * 136];
    const int t = threadIdx.x;
    const int lane = t & 63;
    const int wv = t >> 6;
    const int col = lane & 15, g = lane >> 4;
    const int row0 = blockIdx.x * 32 + wv * 16;
    _Float16* hl = sh[wv];

    // L1: A from hcat, B streamed, C -> hl (bn+relu)
    f16x8 ax[4];
#pragma unroll
    for (int kc = 0; kc < 4; kc++)
        ax[kc] = *(const f16x8*)&hcat[(row0 + col) * 128 + kc * 32 + g * 8];
#pragma unroll
    for (int nt = 0; nt < 8; nt++) {
        int n = nt * 16 + col;
        f32x4 acc;
#pragma unroll
        for (int r = 0; r < 4; r++) acc[r] = 0.f;
#pragma unroll
        for (int kc = 0; kc < 4; kc++) {
            f16x8 bw = *(const f16x8*)&Wc1tG[n * 128 + kc * 32 + g * 8];
            acc = __builtin_amdgcn_mfma_f32_16x16x32_f16(ax[kc], bw, acc,
                                                         0, 0, 0);
        }
        float gn = cg1[n] * BN_INV, bs = cb1[n];
#pragma unroll
        for (int r = 0; r < 4; r++)
            hl[(g * 4 + r) * 136 + n] =
                (_Float16)fmaxf(acc[r] * gn + bs, 0.f);
    }
    // L2: A from hl (all reads precede the overwrites below; same-wave LDS
    // ordering), C -> hl
#pragma unroll
    for (int kc = 0; kc < 4; kc++)
        ax[kc] = *(const f16x8*)&hl[col * 136 + kc * 32 + g * 8];
#pragma unroll
    for (int nt = 0; nt < 8; nt++) {
        int n = nt * 16 + col;
        f32x4 acc;
#pragma unroll
        for (int r = 0; r < 4; r++) acc[r] = 0.f;
#pragma unroll
        for (int kc = 0; kc < 4; kc++) {
            f16x8 bw = *(const f16x8*)&Wc2tG[n * 128 + kc * 32 + g * 8];
            acc = __builtin_amdgcn_mfma_f32_16x16x32_f16(ax[kc], bw, acc,
                                                         0, 0, 0);
        }
        float gn = cg2[n] * BN_INV, bs = cb2[n];
#pragma unroll
        for (int r = 0; r < 4; r++)
            hl[(g * 4 + r) * 136 + n] =
                (_Float16)fmaxf(acc[r] * gn + bs, 0.f);
    }
    // L3: 4 col-tiles kept in registers
#pragma unroll
    for (int kc = 0; kc < 4; kc++)
        ax[kc] = *(const f16x8*)&hl[col * 136 + kc * 32 + g * 8];
    f32x4 accF[4];
#pragma unroll
    for (int nt = 0; nt < 4; nt++) {
        int n = nt * 16 + col;
        f32x4 acc;
        float bias = bc3[n];
#pragma unroll
        for (int r = 0; r < 4; r++) acc[r] = bias;
#pragma unroll
        for (int kc = 0; kc < 4; kc++) {
            f16x8 bw = *(const f16x8*)&Wc3tG[n * 128 + kc * 32 + g * 8];
            acc = __builtin_amdgcn_mfma_f32_16x16x32_f16(ax[kc], bw, acc,
                                                         0, 0, 0);
        }
        accF[nt] = acc;
    }
    // LayerNorm in registers: per-row sums via width-16 shuffles
    float p1[4], p2[4];
#pragma unroll
    for (int r = 0; r < 4; r++) {
        p1[r] = accF[0][r] + accF[1][r] + accF[2][r] + accF[3][r];
        p2[r] = accF[0][r] * accF[0][r] + accF[1][r] * accF[1][r] +
                accF[2][r] * accF[2][r] + accF[3][r] * accF[3][r];
    }
#pragma unroll
    for (int r = 0; r < 4; r++) {
#pragma unroll
        for (int d = 1; d < 16; d <<= 1) {
            p1[r] += __shfl_xor(p1[r], d, 16);
            p2[r] += __shfl_xor(p2[r], d, 16);
        }
    }
    float lngv[4], lnbv[4];
#pragma unroll
    for (int nt = 0; nt < 4; nt++) {
        lngv[nt] = lng[nt * 16 + col];
        lnbv[nt] = lnb[nt * 16 + col];
    }
#pragma unroll
    for (int r = 0; r < 4; r++) {
        float m = p1[r] * (1.f / 64.f);
        float var = p2[r] * (1.f / 64.f) - m * m;
        float inv = 1.f / sqrtf(var + LN_EPS);
        float* dst = out + (row0 + g * 4 + r) * 64;
#pragma unroll
        for (int nt = 0; nt < 4; nt++)
            dst[nt * 16 + col] =
                (accF[nt][r] - m) * inv * lngv[nt] + lnbv[nt];
    }
}

// ---------------------------------------------------------------------------
extern "C" void kernel_launch(void* const* d_in, const int* in_sizes, int n_in,
                              void* d_out, int out_size, void* d_ws,
                              size_t ws_size, hipStream_t stream)
{
    const int* indices = (const int*)d_in[0];
    const float* feats = (const float*)d_in[1];
    const float* Wq = (const float*)d_in[2];
    const float* bq = (const float*)d_in[3];
    const float* Wk = (const float*)d_in[4];
    const float* bk = (const float*)d_in[5];
    const float* Wv = (const float*)d_in[6];
    const float* bv = (const float*)d_in[7];
    const float* Wp1 = (const float*)d_in[8];
    const float* pg = (const float*)d_in[9];
    const float* pb = (const float*)d_in[10];
    const float* Wp2 = (const float*)d_in[11];
    const float* bp2 = (const float*)d_in[12];
    const float* wg1 = (const float*)d_in[13];
    const float* wb1 = (const float*)d_in[14];
    const float* Ww1 = (const float*)d_in[15];
    const float* wg2 = (const float*)d_in[16];
    const float* wb2 = (const float*)d_in[17];
    const float* Ww2 = (const float*)d_in[18];
    const float* Wc1 = (const float*)d_in[20];
    const float* cg1 = (const float*)d_in[21];
    const float* cb1 = (const float*)d_in[22];
    const float* Wc2 = (const float*)d_in[23];
    const float* cg2 = (const float*)d_in[24];
    const float* cb2 = (const float*)d_in[25];
    const float* Wc3 = (const float*)d_in[26];
    const float* bc3 = (const float*)d_in[27];
    const float* lng = (const float*)d_in[28];
    const float* lnb = (const float*)d_in[29];

    float* out = (float*)d_out;
    float* ws = (float*)d_ws;
    float* xq = ws;
    float* xk = xq + N * C;
    float* xv = xk + N * C;
    int* knn = (int*)(xv + N * C);
    _Float16* wt16 = (_Float16*)(knn + N * 16);
    _Float16* W1tG = wt16;              // 128 x 64
    _Float16* W2tG = W1tG + 8192;       // 64 x 128
    _Float16* Wc1tG = W2tG + 8192;      // 128 x 128
    _Float16* Wc2tG = Wc1tG + 16384;    // 128 x 128
    _Float16* Wc3tG = Wc2tG + 16384;    // 64 x 128
    _Float16* hcat = Wc3tG + 8192;      // 8192 x 128 f16

    qkv_knn_kernel<<<1089, 512, 32768, stream>>>(
        (const int4*)indices, knn, feats, Wq, bq, Wk, bk, Wv, bv, xq, xk, xv,
        Ww1, Ww2, Wc1, Wc2, Wc3, W1tG, W2tG, Wc1tG, Wc2tG, Wc3tG, hcat);
    attn_kernel<<<1024, 512, 0, stream>>>(
        (const int4*)indices, knn, xq, xk, xv, Wp1, pg, pb, Wp2, bp2, wg1,
        wb1, W1tG, wg2, wb2, W2tG, hcat);
    head_kernel<<<256, 128, 0, stream>>>(hcat, Wc1tG, cg1, cb1, Wc2tG, cg2,
                                         cb2, Wc3tG, bc3, lng, lnb, out);
}